// Round 3
// baseline (646.460 us; speedup 1.0000x reference)
//
#include <hip/hip_runtime.h>
#include <hip/hip_bf16.h>
#include <stdint.h>

// Problem constants (from reference)
#define S_LEN   2048
#define BATCH   8
#define NPOS    (BATCH * S_LEN)   // 16384 positions
#define NTAB    16
#define EDIM    64
#define KDIM    (NTAB * EDIM)     // 1024 (GEMM K)
#define NOUT    1024              // n_embd (GEMM N)
#define BM      64                // positions per block in fused kernel

typedef float    f32x4_t  __attribute__((ext_vector_type(4)));
typedef __bf16   bf16x8_t __attribute__((ext_vector_type(8)));

// ---------- fp32 -> bf16 round-to-nearest-even ----------
__device__ __forceinline__ unsigned short f2bf(float f) {
    uint32_t u = __float_as_uint(f);
    u += 0x7fffu + ((u >> 16) & 1u);
    return (unsigned short)(u >> 16);
}

// ---------- kernel 1: convert out_proj_w fp32 -> bf16 ----------
__global__ __launch_bounds__(256) void wconv_kernel(const float* __restrict__ W,
                                                    unsigned short* __restrict__ Wb) {
    int i = blockIdx.x * 256 + threadIdx.x;            // over 1024*1024/4 float4s
    float4 v = ((const float4*)W)[i];
    ushort4 o;
    o.x = f2bf(v.x); o.y = f2bf(v.y); o.z = f2bf(v.z); o.w = f2bf(v.w);
    ((ushort4*)Wb)[i] = o;
}

// ---------- kernel 2: fused hash + gather + GEMM ----------
// Block = 64 positions x full N=1024. Each random table row is read exactly
// once (no emb round-trip). K-chunk t = table t's 64 columns of A.
// 8 waves: wave w owns C columns [w*128, w*128+128); acc = 4x8 f32x4 = 128 VGPR.
// A-chunk double-buffered in LDS with XOR swizzle (reg-staged ds_write, so
// swizzle applies to BOTH sides; 128 B row stride would otherwise be a
// 16-way bank conflict on ds_read_b128). Chunk t+1's random gather loads are
// issued before chunk t's MFMAs (T14) so HBM latency hides under compute.
// B-fragments stream from global Wb (2 MB, L2-resident per XCD after first
// pull; 16 rows x 64 B per wave instruction = fully line-coalesced).
__global__ __launch_bounds__(512, 2) void fused_kernel(
        const int*   __restrict__ tok,
        const int*   __restrict__ mults,
        const int*   __restrict__ bias,
        const int*   __restrict__ omask,
        const int*   __restrict__ tsize,
        const int*   __restrict__ toff,
        const float* __restrict__ table,
        const unsigned short* __restrict__ Wb,
        float*       __restrict__ C) {
    __shared__ int rowbuf[BM][NTAB];                       // 4 KB
    __shared__ __align__(16) unsigned short As[2][BM * EDIM]; // 2 x 8 KB

    const int bm   = blockIdx.x;        // 0..255  (exactly 1 block/CU)
    const int tid  = threadIdx.x;
    const int lane = tid & 63;
    const int w    = tid >> 6;          // wave 0..7 -> C col panel w*128
    const int p0   = bm * BM;

    // ---- phase 1: hash all 64x16 (pos, table) pairs (int64-exact in uint64:
    // products < 2^47, all terms non-negative -> matches reference semantics)
    for (int u = tid; u < BM * NTAB; u += 512) {
        const int i = u >> 4, t = u & 15;
        const int p = p0 + i, s = p & (S_LEN - 1);
        uint64_t tk0 = (uint32_t)tok[p];
        uint64_t tk1 = (s >= 1) ? (uint64_t)(uint32_t)tok[p - 1] : 0ull;
        uint64_t tk2 = (s >= 2) ? (uint64_t)(uint32_t)tok[p - 2] : 0ull;
        uint64_t m0 = (uint32_t)mults[t * 3 + 0];
        uint64_t m1 = (uint32_t)mults[t * 3 + 1];
        uint64_t m2 = (uint32_t)mults[t * 3 + 2];
        uint64_t k0v = (uint32_t)omask[0 * NTAB + t];
        uint64_t k1v = (uint32_t)omask[1 * NTAB + t];
        uint64_t k2v = (uint32_t)omask[2 * NTAB + t];
        uint64_t h = (m0 * tk0 * k0v) ^ (m1 * tk1 * k1v) ^ (m2 * tk2 * k2v)
                   ^ (uint64_t)(uint32_t)bias[t];
        rowbuf[i][t] = (int)(h % (uint64_t)(uint32_t)tsize[t]) + toff[t];
    }
    __syncthreads();

    // gather assignment: thread -> (row ru, float4-slot cp); two float4s per
    // thread at slots cp and cp+8 so each load instruction is 128 B contiguous
    const int ru = tid >> 3;            // 0..63
    const int cp = tid & 7;             // 0..7
    const int sw = (ru & 7) << 4;       // LDS XOR swizzle (16 B slot granular)

    // ---- prologue: gather + stage chunk 0
    float4 g0, g1;
    {
        const float4* src = (const float4*)(table + (size_t)rowbuf[ru][0] * EDIM) + cp;
        g0 = src[0]; g1 = src[8];
    }
    {
        ushort4 o0, o1;
        o0.x = f2bf(g0.x); o0.y = f2bf(g0.y); o0.z = f2bf(g0.z); o0.w = f2bf(g0.w);
        o1.x = f2bf(g1.x); o1.y = f2bf(g1.y); o1.z = f2bf(g1.z); o1.w = f2bf(g1.w);
        char* base = (char*)&As[0][0];
        *(ushort4*)(base + ((ru * 128 + cp * 8) ^ sw))       = o0;
        *(ushort4*)(base + ((ru * 128 + (cp + 8) * 8) ^ sw)) = o1;
    }
    __syncthreads();

    f32x4_t acc[4][8] = {};
    const int r16 = lane & 15;
    const int k16 = lane >> 4;          // 0..3
    int cur = 0;

    for (int t = 0; t < NTAB; ++t) {
        // issue next chunk's random gather loads early (hide under MFMA)
        float4 n0, n1;
        if (t + 1 < NTAB) {
            const float4* src = (const float4*)(table + (size_t)rowbuf[ru][t + 1] * EDIM) + cp;
            n0 = src[0]; n1 = src[8];
        }

        // A-fragments from swizzled LDS (same mapping as verified GEMM:
        // frag row = m*16 + r16, k-offset = ks*32 + k16*8 bf16 elements)
        bf16x8_t af[4][2];
        #pragma unroll
        for (int m = 0; m < 4; ++m)
            #pragma unroll
            for (int ks = 0; ks < 2; ++ks) {
                const int row = m * 16 + r16;
                const int off = (row * 128 + ks * 64 + k16 * 16) ^ ((row & 7) << 4);
                af[m][ks] = *(const bf16x8_t*)((const char*)&As[cur][0] + off);
            }

        // B-fragments straight from global Wb (L2-hot) + MFMA
        const unsigned short* Bbase = Wb + (size_t)(w * 128) * KDIM + t * 64 + k16 * 8;
        #pragma unroll
        for (int n = 0; n < 8; ++n) {
            const unsigned short* bp = Bbase + (size_t)(n * 16 + r16) * KDIM;
            bf16x8_t b0 = *(const bf16x8_t*)(bp);
            bf16x8_t b1 = *(const bf16x8_t*)(bp + 32);
            #pragma unroll
            for (int m = 0; m < 4; ++m) {
                acc[m][n] = __builtin_amdgcn_mfma_f32_16x16x32_bf16(af[m][0], b0, acc[m][n], 0, 0, 0);
                acc[m][n] = __builtin_amdgcn_mfma_f32_16x16x32_bf16(af[m][1], b1, acc[m][n], 0, 0, 0);
            }
        }

        __syncthreads();                 // all waves done reading As[cur]
        if (t + 1 < NTAB) {              // write-late: cvt + stage into As[cur^1]
            ushort4 o0, o1;
            o0.x = f2bf(n0.x); o0.y = f2bf(n0.y); o0.z = f2bf(n0.z); o0.w = f2bf(n0.w);
            o1.x = f2bf(n1.x); o1.y = f2bf(n1.y); o1.z = f2bf(n1.z); o1.w = f2bf(n1.w);
            char* base = (char*)&As[cur ^ 1][0];
            *(ushort4*)(base + ((ru * 128 + cp * 8) ^ sw))       = o0;
            *(ushort4*)(base + ((ru * 128 + (cp + 8) * 8) ^ sw)) = o1;
        }
        __syncthreads();                 // staged chunk visible to all waves
        cur ^= 1;
    }

    // ---- epilogue: C/D layout col = lane&15 (n), row = (lane>>4)*4 + reg (m)
    #pragma unroll
    for (int m = 0; m < 4; ++m)
        #pragma unroll
        for (int n = 0; n < 8; ++n)
            #pragma unroll
            for (int r = 0; r < 4; ++r)
                C[(size_t)(p0 + m * 16 + k16 * 4 + r) * NOUT + w * 128 + n * 16 + r16] = acc[m][n][r];
}

extern "C" void kernel_launch(void* const* d_in, const int* in_sizes, int n_in,
                              void* d_out, int out_size, void* d_ws, size_t ws_size,
                              hipStream_t stream) {
    const int*   tok   = (const int*)d_in[0];
    const float* table = (const float*)d_in[1];
    const float* W     = (const float*)d_in[2];
    const int*   mults = (const int*)d_in[3];
    const int*   bias  = (const int*)d_in[4];
    const int*   omask = (const int*)d_in[5];
    const int*   tsize = (const int*)d_in[6];
    const int*   toff  = (const int*)d_in[7];
    float*       out   = (float*)d_out;

    // workspace layout: Wb bf16 (2 MB) only — emb round-trip eliminated
    unsigned short* Wb = (unsigned short*)d_ws;

    wconv_kernel<<<(NOUT * KDIM / 4) / 256, 256, 0, stream>>>(W, Wb);
    fused_kernel<<<NPOS / BM, 512, 0, stream>>>(tok, mults, bias, omask, tsize, toff,
                                                table, Wb, out);
}